// Round 8
// baseline (110.409 us; speedup 1.0000x reference)
//
#include <hip/hip_runtime.h>
#include <math.h>

// ChamferDistanceL1: B=8, N=M=4096, fp32.
// R8 = R7 with the compile fix: __builtin_amdgcn_update_dpp needs a
// constant-int dpp_ctrl -> templated helper.
// R7 theory: symmetric single-pass — d[i,j] feeds BOTH row-min (cham_x) and
// col-min (cham_y); halves distance compute vs the two-pass R4/R6 structure.
//  - block = (b, 32-row x-tile) scans all 4096 y cols in 1024-pt LDS slices.
//  - lanes in quads: 4 lanes x 8 rows; each of 128 quads owns 8 cols/slice.
//    col-min per j: per-lane min3 chain then DPP quad_perm xor1/xor2 min
//    (VALU pipe, not LDS swizzle -> LDS pipe stays ~58% loaded).
//  - per-block col-mins -> plain coalesced stores to ws (no atomics);
//    row-mins final per block -> ws. finalize: min over 128 i-tiles (16 MB),
//    sum, one atomicAdd per block into memset-zeroed d_out.
// Note: total dur includes a fixed ~40us harness d_ws re-poison fill (R6
// rocprof: fillBufferAligned 268MB @84% HBM peak) — not actionable.

#define BLK 512
#define TI 32        // x-rows per block
#define RPL 8        // rows per lane (4 lanes * 8 = 32)
#define SLICE 1024   // y-points staged in LDS per slice
#define JPG 8        // cols per quad per slice (1024 / 128 quads)
#define NGRP 128     // quads per block (BLK/4)

template <int CTRL>
__device__ __forceinline__ float dpp_min_xor(float v) {
  // quad_perm lane swap inside each quad; 0xB1 = xor1, 0x4E = xor2.
  int s = __builtin_amdgcn_update_dpp(0, __float_as_int(v), CTRL, 0xF, 0xF, true);
  return fminf(v, __int_as_float(s));
}

__global__ __launch_bounds__(BLK) void chamfer_sym_kernel(
    const float* __restrict__ x, const float* __restrict__ y,
    float* __restrict__ colpart, float* __restrict__ rowmin) {
  __shared__ float4 sdb[NGRP * (JPG + 1)];  // row pad +1: stride 36 dwords ==
                                            // 4 mod 32 -> quads' reads spread
  __shared__ float colsh[4096];             // block col-mins (16 KB)
  __shared__ float rowsh[8][TI];            // cross-wave row partials

  const int b = blockIdx.y;
  const int it = blockIdx.x;
  const float* __restrict__ xb = x + (size_t)b * 4096 * 3;
  const float* __restrict__ yb = y + (size_t)b * 4096 * 3;

  const int t = threadIdx.x;
  const int g = t >> 2;  // quad id [0,128)
  const int u = t & 3;   // lane-in-quad

  float qx[RPL], qy[RPL], qz[RPL], rmin[RPL];
  const int r0 = it * TI + u * RPL;
#pragma unroll
  for (int k = 0; k < RPL; ++k) {
    qx[k] = xb[3 * (r0 + k) + 0];
    qy[k] = xb[3 * (r0 + k) + 1];
    qz[k] = xb[3 * (r0 + k) + 2];
    rmin[k] = 3.0e38f;
  }

  for (int s0 = 0; s0 < 4096; s0 += SLICE) {
#pragma unroll
    for (int r = 0; r < SLICE / BLK; ++r) {
      const int p = t + r * BLK;
      const int j = s0 + p;
      sdb[(p >> 3) * (JPG + 1) + (p & 7)] =
          make_float4(yb[3 * j], yb[3 * j + 1], yb[3 * j + 2], 0.0f);
    }
    __syncthreads();

    const float4* gb = &sdb[g * (JPG + 1)];
#pragma unroll
    for (int tt = 0; tt < JPG; tt += 2) {
      const float4 p0 = gb[tt];
      const float4 p1 = gb[tt + 1];
      float cm0 = 3.0e38f, cm1 = 3.0e38f;
#pragma unroll
      for (int k = 0; k < RPL; k += 2) {
        const float d0a = fabsf(qx[k] - p0.x) + fabsf(qy[k] - p0.y) + fabsf(qz[k] - p0.z);
        const float d1a = fabsf(qx[k] - p1.x) + fabsf(qy[k] - p1.y) + fabsf(qz[k] - p1.z);
        const float d0b = fabsf(qx[k+1] - p0.x) + fabsf(qy[k+1] - p0.y) + fabsf(qz[k+1] - p0.z);
        const float d1b = fabsf(qx[k+1] - p1.x) + fabsf(qy[k+1] - p1.y) + fabsf(qz[k+1] - p1.z);
        rmin[k]     = fminf(fminf(rmin[k],     d0a), d1a);   // v_min3
        rmin[k + 1] = fminf(fminf(rmin[k + 1], d0b), d1b);
        cm0 = fminf(fminf(cm0, d0a), d0b);
        cm1 = fminf(fminf(cm1, d1a), d1b);
      }
      // min across the 4 quad lanes (covers all 32 rows) — VALU DPP
      cm0 = dpp_min_xor<0xB1>(cm0); cm0 = dpp_min_xor<0x4E>(cm0);
      cm1 = dpp_min_xor<0xB1>(cm1); cm1 = dpp_min_xor<0x4E>(cm1);
      if (u == 0) {  // quad owner writes its 2 cols
        const int j = s0 + g * JPG + tt;
        colsh[j] = cm0;
        colsh[j + 1] = cm1;
      }
    }
    __syncthreads();
  }

  // rows: combine across the 16 quads of each wave (lane bits 2..5), then waves
#pragma unroll
  for (int k = 0; k < RPL; ++k) {
    float m = rmin[k];
    m = fminf(m, __shfl_xor(m, 4, 64));
    m = fminf(m, __shfl_xor(m, 8, 64));
    m = fminf(m, __shfl_xor(m, 16, 64));
    m = fminf(m, __shfl_xor(m, 32, 64));
    rmin[k] = m;
  }
  const int w = t >> 6;
  const int l = t & 63;
  if (l < 4) {
#pragma unroll
    for (int k = 0; k < RPL; ++k) rowsh[w][l * RPL + k] = rmin[k];
  }
  __syncthreads();
  if (t < TI) {
    float m = rowsh[0][t];
#pragma unroll
    for (int ww = 1; ww < 8; ++ww) m = fminf(m, rowsh[ww][t]);
    rowmin[(size_t)b * 4096 + it * TI + t] = m;  // final: block scanned all j
  }
  // block col-mins: coalesced store of colsh to ws (min over THIS i-tile only)
  float* cp = colpart + (size_t)(b * gridDim.x + it) * 4096;
#pragma unroll
  for (int r = 0; r < 8; ++r) cp[t + r * BLK] = colsh[t + r * BLK];
}

__global__ __launch_bounds__(256) void chamfer_sym_finalize(
    const float* __restrict__ colpart, const float* __restrict__ rowmin,
    float* __restrict__ out, float sx, float sy) {
  // 32 blocks: b = blk>>2, j-quarter = (blk&3)*1024. Min over 128 i-tiles.
  const int b = blockIdx.x >> 2;
  const int jq = (blockIdx.x & 3) * 1024;
  const int t = threadIdx.x;
  const float4* cp4 = (const float4*)(colpart + (size_t)b * 128 * 4096 + jq);
  float4 m = cp4[t];
#pragma unroll 4
  for (int it = 1; it < 128; ++it) {
    const float4 v = cp4[(size_t)it * 1024 + t];
    m.x = fminf(m.x, v.x); m.y = fminf(m.y, v.y);
    m.z = fminf(m.z, v.z); m.w = fminf(m.w, v.w);
  }
  float acc = ((m.x + m.y) + (m.z + m.w)) * sy;
  const float4 rv = ((const float4*)rowmin)[(size_t)blockIdx.x * 256 + t];
  acc += ((rv.x + rv.y) + (rv.z + rv.w)) * sx;
#pragma unroll
  for (int o = 32; o > 0; o >>= 1) acc += __shfl_down(acc, o, 64);
  __shared__ float ws4[4];
  if ((t & 63) == 0) ws4[t >> 6] = acc;
  __syncthreads();
  if (t == 0) atomicAdd(out, (ws4[0] + ws4[1]) + (ws4[2] + ws4[3]));
}

// ---------------- generic fallback (non-4096 shapes): proven R6 path --------
#define GBLK 512
#define GQPB 64
#define GQPT 4
#define GSLICE 1024
#define GGRANGE 32
#define GNWAVE 8

__global__ __launch_bounds__(GBLK) void chamfer_generic_kernel(
    const float* __restrict__ x, const float* __restrict__ y,
    float* __restrict__ partial, int N, int M, float sx, float sy) {
  __shared__ float4 sdb[32][GGRANGE + 1];
  __shared__ float pmin[GNWAVE][GQPB];
  const int dir = blockIdx.z;
  const int b = blockIdx.y;
  const float* __restrict__ q  = dir ? y : x;
  const float* __restrict__ db = dir ? x : y;
  const int Nq  = dir ? M : N;
  const int Ndb = dir ? N : M;
  const float scale = dir ? sy : sx;
  const float* __restrict__ qb  = q  + (size_t)b * Nq  * 3;
  const float* __restrict__ dbb = db + (size_t)b * Ndb * 3;
  const int t = threadIdx.x;
  const int g = t >> 4;
  const int u = t & 15;
  const int q0 = blockIdx.x * GQPB;
  float qx[GQPT], qy[GQPT], qz[GQPT], dmin[GQPT];
#pragma unroll
  for (int k = 0; k < GQPT; ++k) {
    int qi = q0 + u + 16 * k;
    if (qi >= Nq) qi = Nq - 1;
    qx[k] = qb[3 * qi + 0]; qy[k] = qb[3 * qi + 1]; qz[k] = qb[3 * qi + 2];
    dmin[k] = 3.0e38f;
  }
  for (int s0 = 0; s0 < Ndb; s0 += GSLICE) {
    const int send = min(GSLICE, Ndb - s0);
    for (int p = t; p < send; p += GBLK) {
      const int j = s0 + p;
      sdb[p >> 5][p & 31] =
          make_float4(dbb[3 * j + 0], dbb[3 * j + 1], dbb[3 * j + 2], 0.0f);
    }
    __syncthreads();
    const int lim = min(GGRANGE, max(0, send - g * GGRANGE));
    for (int tt = 0; tt < lim; ++tt) {
      const float4 p0 = sdb[g][tt];
#pragma unroll
      for (int k = 0; k < GQPT; ++k) {
        const float d0 =
            fabsf(qx[k] - p0.x) + fabsf(qy[k] - p0.y) + fabsf(qz[k] - p0.z);
        dmin[k] = fminf(dmin[k], d0);
      }
    }
    __syncthreads();
  }
#pragma unroll
  for (int k = 0; k < GQPT; ++k) {
    float m = dmin[k];
    m = fminf(m, __shfl_xor(m, 16, 64));
    m = fminf(m, __shfl_xor(m, 32, 64));
    dmin[k] = m;
  }
  const int w = t >> 6;
  const int l = t & 63;
  if (l < 16) {
#pragma unroll
    for (int k = 0; k < GQPT; ++k) pmin[w][l + 16 * k] = dmin[k];
  }
  __syncthreads();
  if (t < GQPB) {
    float m = pmin[0][t];
#pragma unroll
    for (int ww = 1; ww < GNWAVE; ++ww) m = fminf(m, pmin[ww][t]);
    if (q0 + t >= Nq) m = 0.0f;
#pragma unroll
    for (int o = 32; o > 0; o >>= 1) m += __shfl_down(m, o, 64);
    if (t == 0) {
      const int bid =
          (blockIdx.z * gridDim.y + blockIdx.y) * gridDim.x + blockIdx.x;
      partial[bid] = m * scale;
    }
  }
}

__global__ __launch_bounds__(256) void chamfer_generic_finalize(
    const float* __restrict__ part, float* __restrict__ out, int n) {
  float s = 0.0f;
  for (int i = threadIdx.x; i < n; i += 256) s += part[i];
#pragma unroll
  for (int o = 32; o > 0; o >>= 1) s += __shfl_down(s, o, 64);
  __shared__ float ws[4];
  const int w = threadIdx.x >> 6;
  if ((threadIdx.x & 63) == 0) ws[w] = s;
  __syncthreads();
  if (threadIdx.x == 0) out[0] = ws[0] + ws[1] + ws[2] + ws[3];
}

extern "C" void kernel_launch(void* const* d_in, const int* in_sizes, int n_in,
                              void* d_out, int out_size, void* d_ws, size_t ws_size,
                              hipStream_t stream) {
  const float* x = (const float*)d_in[0];
  const float* y = (const float*)d_in[1];
  const int B = 8;
  const int N = in_sizes[0] / (B * 3);
  const int M = in_sizes[1] / (B * 3);
  float* out = (float*)d_out;
  const float sx = 1.0f / (float)(B * N);
  const float sy = 1.0f / (float)(B * M);

  if (N == 4096 && M == 4096) {
    float* colpart = (float*)d_ws;                        // 8*128*4096 f (16MB)
    float* rowmin = colpart + (size_t)8 * 128 * 4096;     // 32768 f (128KB)
    (void)hipMemsetAsync(out, 0, sizeof(float), stream);  // atomicAdd target
    chamfer_sym_kernel<<<dim3(128, 8), BLK, 0, stream>>>(x, y, colpart, rowmin);
    chamfer_sym_finalize<<<32, 256, 0, stream>>>(colpart, rowmin, out, sx, sy);
  } else {
    float* partial = (float*)d_ws;
    const int mx = (N > M) ? N : M;
    dim3 grd((mx + GQPB - 1) / GQPB, B, 2);
    chamfer_generic_kernel<<<grd, GBLK, 0, stream>>>(x, y, partial, N, M, sx, sy);
    chamfer_generic_finalize<<<1, 256, 0, stream>>>(
        partial, out, (int)(grd.x * grd.y * grd.z));
  }
}